// Round 11
// baseline (18799.103 us; speedup 1.0000x reference)
//
#include <hip/hip_runtime.h>
#include <hip/hip_bf16.h>
#include <cstdint>
#include <cstddef>

// ---------------------------------------------------------------------------
// FlumenHead: encoder MLP (32->512->512->1024) + 2048-step LSTM (D=9, F=1024)
// v10: batch-pipelined sub-steps + parity-validated publishes.
//  - Batches are independent recurrent streams: step t = 4 sub-steps (n-tiles
//    j=0..3). n-tile j's h is published right after its cell update and
//    consumed 4 sub-steps later -> every LLC round-trip hides under compute.
//  - Self-validating data: |h|<1 so bf16 bit14==0; publishes XOR bit14 with
//    generation parity p=(t>>1)&1. Fill loads ARE the poll (no tags, no
//    producer vmcnt-before-tag). Torn/stale chunks fail parity and re-poll.
//  - Buffers poisoned each launch (fails both parities); t=0 image in a
//    separate init region ordered by kernel launch.
//  - Per sub-step: v9-proven internals ((mtp,kh) waves, Apin[2][16]=128 regs,
//    fragment-linear conflict-free LDS, partial-sum exchange, 3 barriers).
// ---------------------------------------------------------------------------

typedef __bf16 bf16x8_t __attribute__((ext_vector_type(8)));
typedef float f32x4_t __attribute__((ext_vector_type(4)));
typedef unsigned int u32x4_t __attribute__((ext_vector_type(4)));
typedef unsigned long long u64_t;
typedef unsigned long long u64x2_t __attribute__((ext_vector_type(2)));
typedef unsigned short u16x4_t __attribute__((ext_vector_type(4)));

// workspace layout (bytes); total ~17.7 MB
#define WS_HBUF    0          // u16 [init 128K][buf0 128K][buf1 128K]  384 KB
#define WS_WSHUF   393216     // u16 Wshuf[256 mt][32 kt][64 ln][8]       8 MB
#define WS_WAUG    8781824    // u16 WaugI[256 mt][64 ln][8]            256 KB
#define WS_XHAT    9043968    // u16 Xhat[2048 t][64 b][32] bf16          8 MB
#define WS_H1      17432576   // f32 h1[64][512]                        128 KB
#define WS_H2      17563648   // f32 h2[64][512]                        128 KB

#define PAR_M 0x40004000u

__device__ __forceinline__ unsigned short f2bf(float f) {
  unsigned int u = __float_as_uint(f);
  u = (u + 0x7fffu + ((u >> 16) & 1u)) >> 16;   // RNE
  return (unsigned short)u;
}
__device__ __forceinline__ float sigm(float x) { return 1.f / (1.f + __expf(-x)); }
__device__ __forceinline__ float tanh_f(float x) {
  float e = __expf(-2.f * fabsf(x));
  float r = (1.f - e) / (1.f + e);
  return copysignf(r, x);
}

// ---------------------------- encoder ----------------------------

__global__ void flumen_enc1(const float* __restrict__ x, const float* __restrict__ W,
                            const float* __restrict__ b, float* __restrict__ h1) {
  const int bb = blockIdx.x;   // batch 0..63
  const int o  = threadIdx.x;  // 0..511
  const f32x4_t* xr = (const f32x4_t*)(x + bb * 32);
  const f32x4_t* wr = (const f32x4_t*)(W + o * 32);
  float acc = b[o];
#pragma unroll
  for (int q = 0; q < 8; ++q) {
    f32x4_t xv = xr[q], wv = wr[q];
    acc += xv[0] * wv[0] + xv[1] * wv[1] + xv[2] * wv[2] + xv[3] * wv[3];
  }
  h1[bb * 512 + o] = fmaxf(acc, 0.f);
}

__global__ void flumen_enc2(const float* __restrict__ in, const float* __restrict__ W,
                            const float* __restrict__ bv, float* __restrict__ outb) {
  __shared__ float s[64 * 256];
  const int tid = threadIdx.x;
  const int ol = tid & 63, bg = tid >> 6;
  const int o = blockIdx.x * 64 + ol;
  float bias = bv[o];
  float acc[8];
#pragma unroll
  for (int q = 0; q < 8; ++q) acc[q] = bias;
  for (int p = 0; p < 2; ++p) {
    __syncthreads();
    for (int i = tid; i < 4096; i += 512) {
      int flat = i * 4;
      int bb = flat >> 8, kk = flat & 255;
      *(f32x4_t*)(s + flat) = *(const f32x4_t*)(in + bb * 512 + p * 256 + kk);
    }
    __syncthreads();
    for (int kk = 0; kk < 256; kk += 4) {
      f32x4_t wv = *(const f32x4_t*)(W + o * 512 + p * 256 + kk);
#pragma unroll
      for (int j = 0; j < 4; ++j) {
        float wj = wv[j];
#pragma unroll
        for (int q = 0; q < 8; ++q)
          acc[q] += wj * s[(bg * 8 + q) * 256 + kk + j];
      }
    }
  }
#pragma unroll
  for (int q = 0; q < 8; ++q)
    outb[(bg * 8 + q) * 512 + o] = fmaxf(acc[q], 0.f);
}

__global__ void flumen_enc3(const float* __restrict__ in, const float* __restrict__ W,
                            const float* __restrict__ bv, float* __restrict__ dout,
                            unsigned short* __restrict__ hbuf) {
  __shared__ float s[64 * 256];
  const int tid = threadIdx.x;
  const int ol = tid & 63, bg = tid >> 6;
  const int o = blockIdx.x * 64 + ol;   // 0..1023
  float bias = bv[o];
  float acc[8];
#pragma unroll
  for (int q = 0; q < 8; ++q) acc[q] = bias;
  for (int p = 0; p < 2; ++p) {
    __syncthreads();
    for (int i = tid; i < 4096; i += 512) {
      int flat = i * 4;
      int bb = flat >> 8, kk = flat & 255;
      *(f32x4_t*)(s + flat) = *(const f32x4_t*)(in + bb * 512 + p * 256 + kk);
    }
    __syncthreads();
    for (int kk = 0; kk < 256; kk += 4) {
      f32x4_t wv = *(const f32x4_t*)(W + o * 512 + p * 256 + kk);
#pragma unroll
      for (int j = 0; j < 4; ++j) {
        float wj = wv[j];
#pragma unroll
        for (int q = 0; q < 8; ++q)
          acc[q] += wj * s[(bg * 8 + q) * 256 + kk + j];
      }
    }
  }
  float* out_hseq = dout + 65536;
#pragma unroll
  for (int q = 0; q < 8; ++q) {
    int bb = bg * 8 + q;
    float v = acc[q];
    out_hseq[(size_t)bb * 2097152 + o] = v;   // h_seq[b][0][o]
    // init image (fragment-linear, no parity): block=(b>>4)*32+(o>>5),
    // lane=((o>>3)&3)*16+(b&15), e=o&7
    int blk  = (bb >> 4) * 32 + (o >> 5);
    int lane = ((o >> 3) & 3) * 16 + (bb & 15);
    hbuf[blk * 512 + lane * 8 + (o & 7)] = f2bf(v);
  }
}

// ---------------------------- precompute ----------------------------

// Poison both LSTM double-buffers so stale data fails BOTH parity checks.
// Pattern per 16B chunk: {M,0,M,0}. Covers hbuf bytes 131072..393216.
__global__ void flumen_scrub(unsigned int* __restrict__ hb) {
  int i = blockIdx.x * 512 + threadIdx.x;   // 0..16383
  u32x4_t pat = {PAR_M, 0u, PAR_M, 0u};
  *(u32x4_t*)(hb + 32768 + i * 4) = pat;
}

// Gate-interleaved A fragments: Wshuf[mt][kt][lane][8],
// A row r = lane&15 -> gate g = r&3, feature f = mt*4 + (r>>2);
// k = kt*32 + (lane>>4)*8 + e; src = w_hh[(g*1024+f)*1024 + k].
__global__ void flumen_wshuf(const float* __restrict__ src, unsigned short* __restrict__ dst) {
  int idx = blockIdx.x * 512 + threadIdx.x;      // 0..524287
  int lane = idx & 63, kt = (idx >> 6) & 31, mt = idx >> 11;
  int r = lane & 15;
  int g = r & 3, f = mt * 4 + (r >> 2);
  int k0 = kt * 32 + (lane >> 4) * 8;
  const float* sp = src + (size_t)(g * 1024 + f) * 1024 + k0;
  f32x4_t v0 = *(const f32x4_t*)(sp);
  f32x4_t v1 = *(const f32x4_t*)(sp + 4);
  u16x4_t o0, o1;
#pragma unroll
  for (int j = 0; j < 4; ++j) { o0[j] = f2bf(v0[j]); o1[j] = f2bf(v1[j]); }
  u16x4_t* dp = (u16x4_t*)(dst + (size_t)idx * 8);
  dp[0] = o0; dp[1] = o1;
}

// Gate-interleaved augmented fragments: WaugI[mt][lane][8], K=32:
// k<9 -> w_ih[(g*1024+f)*9+k], k==9 -> bias[g*1024+f], else 0.
__global__ void flumen_waugi(const float* __restrict__ wih, const float* __restrict__ bias,
                             unsigned short* __restrict__ dst) {
  int idx = blockIdx.x * 512 + threadIdx.x;      // 0..16383
  int lane = idx & 63, mt = idx >> 6;
  int r = lane & 15;
  int g = r & 3, f = mt * 4 + (r >> 2);
  int k0 = (lane >> 4) * 8;
  unsigned short o[8];
#pragma unroll
  for (int j = 0; j < 8; ++j) {
    int k = k0 + j;
    float v = (k < 9) ? wih[(size_t)(g * 1024 + f) * 9 + k]
                      : (k == 9 ? bias[g * 1024 + f] : 0.f);
    o[j] = f2bf(v);
  }
  u16x4_t* dp = (u16x4_t*)(dst + (size_t)idx * 8);
  dp[0] = *(u16x4_t*)&o[0];
  dp[1] = *(u16x4_t*)&o[4];
}

// Xhat[t][b][0..8]=x[b][t][:], [9]=1.0, rest 0. grid=2048.
__global__ void flumen_convx(const float* __restrict__ xin, unsigned short* __restrict__ dst) {
  int i = (blockIdx.x * 512 + threadIdx.x) * 4;   // elem index, 4 at a time
  int b = i >> 16, t = (i >> 5) & 2047, c0 = i & 31;
  u16x4_t o;
#pragma unroll
  for (int j = 0; j < 4; ++j) {
    int cc = c0 + j;
    float v = (cc < 9) ? xin[((size_t)b * 2048 + t) * 9 + cc] : (cc == 9 ? 1.f : 0.f);
    o[j] = f2bf(v);
  }
  *(u16x4_t*)(dst + ((size_t)t * 64 + b) * 32 + c0) = o;
}

// ---------------------------- persistent LSTM ----------------------------
// 32 WGs x 512 thr, 1 WG/CU (145 KB LDS). WG w owns features [32w,32w+32)
// = M-tiles w*8..w*8+8 (gate-interleaved). Wave = kh*4+mtp (v9 shape).
// Step t = 4 sub-steps (n-tile j): fill j (parity-validated, pre-issued one
// sub-step early) -> B_fill -> issue next loads -> K-loop(n=j) -> partials
// -> B_part -> kh0 reduce+cell+stage -> B_hs -> wave4 publish (parity) /
// waves 5,6 h_seq. Publishes land 4 sub-steps before consumption -> warm.
__global__ __launch_bounds__(512, 1) void flumen_lstm(
    const unsigned short* __restrict__ Wshuf,
    const unsigned short* __restrict__ WaugI,
    const unsigned short* __restrict__ Xhat,
    unsigned short* hbuf, float* out)
{
  __shared__ __align__(16) char smem[148480];
  char*  h_lds = smem;                           // 128KB image (4 n-regions)
  float* hs    = (float*)(smem + 131072);        // [64][36] f32 staging
  float* pbuf  = (float*)(smem + 140288);        // 8KB partial exchange

  float* out_hlast = out;
  float* out_hseq  = out + 65536;
  const int w    = blockIdx.x;       // 0..31
  const int tid  = threadIdx.x;
  const int lane = tid & 63;
  const int wave = tid >> 6;         // 0..7
  const int mtp  = wave & 3;
  const int kh   = wave >> 2;
  const int l15  = lane & 15;
  const int l4   = lane >> 4;

  // pinned A: 2 M-tiles x 16 K-frags (this wave's K-half) = 128 regs
  bf16x8_t Apin[2][16];
#pragma unroll
  for (int mtl = 0; mtl < 2; ++mtl) {
    const char* ap = (const char*)Wshuf + (size_t)(w * 8 + mtp * 2 + mtl) * 32768
                   + (size_t)(kh * 16) * 1024 + lane * 16;
#pragma unroll
    for (int k16 = 0; k16 < 16; ++k16)
      Apin[mtl][k16] = *(const bf16x8_t*)(ap + k16 * 1024);
  }
  bf16x8_t wfragI[2];
#pragma unroll
  for (int mtl = 0; mtl < 2; ++mtl)
    wfragI[mtl] = *(const bf16x8_t*)((const char*)WaugI
                                     + (size_t)(w * 8 + mtp * 2 + mtl) * 1024 + lane * 16);

  float carr[2][4] = {{0.f,0.f,0.f,0.f},{0.f,0.f,0.f,0.f}};

  // in-flight fill chunks (4 x 16B per thread = one n-tile's 32KB per WG)
  u32x4_t v[4];
  {
    const char* src = (const char*)hbuf + tid * 16;   // (t=0, j=0): init region
#pragma unroll
    for (int i = 0; i < 4; ++i)
      asm volatile("global_load_dwordx4 %0, %1, off sc1"
                   : "=v"(v[i]) : "v"(src + i * 8192) : "memory");
  }

  for (int t = 0; t < 2048; ++t) {
    const unsigned p  = (unsigned)((t >> 1) & 1);
    const bool checkp = (t > 0);
    const unsigned pm = (checkp && p) ? PAR_M : 0u;

    for (int j = 0; j < 4; ++j) {
      // ---- complete fill (t,j): loads were issued one sub-step ago ----
      asm volatile("s_waitcnt vmcnt(0)" ::: "memory");
      if (checkp) {
        const char* src = (const char*)hbuf + (size_t)(131072 * (1 + (t & 1)))
                        + j * 32768 + tid * 16;
        int iter = 0;
        while (true) {
          unsigned a = 0xFFFFFFFFu, o = 0u;
#pragma unroll
          for (int i = 0; i < 4; ++i)
#pragma unroll
            for (int d = 0; d < 4; ++d) { a &= v[i][d]; o |= v[i][d]; }
          bool valid = p ? ((a & PAR_M) == PAR_M) : ((o & PAR_M) == 0u);
          if (__all(valid) || ++iter >= (1 << 18)) break;
#pragma unroll
          for (int i = 0; i < 4; ++i)
            asm volatile("global_load_dwordx4 %0, %1, off sc1"
                         : "=v"(v[i]) : "v"(src + i * 8192) : "memory");
          asm volatile("s_waitcnt vmcnt(0)" ::: "memory");
        }
      }
      __builtin_amdgcn_sched_barrier(0);
      {
        u32x4_t pmv = {pm, pm, pm, pm};
#pragma unroll
        for (int i = 0; i < 4; ++i)
          *(u32x4_t*)(h_lds + j * 32768 + tid * 16 + i * 8192) = v[i] ^ pmv;
      }
      __syncthreads();   // B_fill: n-tile j image ready

      // ---- issue next sub-step's loads (fly under compute) ----
      if (!(t == 2047 && j == 3)) {
        const int tn = (j == 3) ? t + 1 : t;
        const int jn = (j + 1) & 3;
        const char* src = (const char*)hbuf
            + (tn == 0 ? (size_t)0 : (size_t)(131072 * (1 + (tn & 1))))
            + jn * 32768 + tid * 16;
#pragma unroll
        for (int i = 0; i < 4; ++i)
          asm volatile("global_load_dwordx4 %0, %1, off sc1"
                       : "=v"(v[i]) : "v"(src + i * 8192) : "memory");
      }

      // ---- compute n-tile j ----
      f32x4_t acc[2];
      if (kh == 0) {
        bf16x8_t xf = *(const bf16x8_t*)(Xhat + ((size_t)t * 64 + j * 16 + l15) * 32 + l4 * 8);
#pragma unroll
        for (int mtl = 0; mtl < 2; ++mtl)
          acc[mtl] = __builtin_amdgcn_mfma_f32_16x16x32_bf16(
              wfragI[mtl], xf, (f32x4_t){0.f, 0.f, 0.f, 0.f}, 0, 0, 0);
      } else {
        acc[0] = (f32x4_t){0.f, 0.f, 0.f, 0.f};
        acc[1] = (f32x4_t){0.f, 0.f, 0.f, 0.f};
      }
      {
        const char* bb = h_lds + j * 32768 + (size_t)(kh * 16) * 1024 + lane * 16;
#pragma unroll
        for (int k16 = 0; k16 < 16; ++k16) {
          bf16x8_t bf = *(const bf16x8_t*)(bb + k16 * 1024);
          acc[0] = __builtin_amdgcn_mfma_f32_16x16x32_bf16(Apin[0][k16], bf, acc[0], 0, 0, 0);
          acc[1] = __builtin_amdgcn_mfma_f32_16x16x32_bf16(Apin[1][k16], bf, acc[1], 0, 0, 0);
        }
      }
      if (kh == 1) {
#pragma unroll
        for (int mtl = 0; mtl < 2; ++mtl)
          *(f32x4_t*)(pbuf + (size_t)((mtp * 2 + mtl) * 64 + lane) * 4) = acc[mtl];
      }
      __syncthreads();   // B_part

      if (kh == 0) {
#pragma unroll
        for (int mtl = 0; mtl < 2; ++mtl) {
          f32x4_t pt = *(const f32x4_t*)(pbuf + (size_t)((mtp * 2 + mtl) * 64 + lane) * 4);
          f32x4_t s = acc[mtl] + pt;
          float c = sigm(s[1]) * carr[mtl][j] + sigm(s[0]) * tanh_f(s[2]);
          carr[mtl][j] = c;
          float h = sigm(s[3]) * tanh_f(c);
          const int fl = (mtp * 2 + mtl) * 4 + l4;
          if (t < 2047) {
            hs[(j * 16 + l15) * 36 + fl] = h;
          } else {
            out_hlast[(j * 16 + l15) * 1024 + w * 32 + fl] = h;
          }
        }
      }
      __syncthreads();   // B_hs

      if (t < 2047) {
        if (wave == 4) {
          // publish block (n=j, kt=w), gen t+1, parity-encoded, 1KB contiguous
          const int b = j * 16 + l15;
          const float* hp = hs + b * 36 + l4 * 8;
          f32x4_t u0 = *(const f32x4_t*)(hp);
          f32x4_t u1 = *(const f32x4_t*)(hp + 4);
          u64_t lo = (u64_t)f2bf(u0[0]) | ((u64_t)f2bf(u0[1]) << 16)
                   | ((u64_t)f2bf(u0[2]) << 32) | ((u64_t)f2bf(u0[3]) << 48);
          u64_t hi = (u64_t)f2bf(u1[0]) | ((u64_t)f2bf(u1[1]) << 16)
                   | ((u64_t)f2bf(u1[2]) << 32) | ((u64_t)f2bf(u1[3]) << 48);
          if (((t + 1) >> 1) & 1) {
            lo ^= 0x4000400040004000ULL;
            hi ^= 0x4000400040004000ULL;
          }
          u64x2_t qv = {lo, hi};
          char* dst = (char*)hbuf + (size_t)(131072 * (1 + ((t + 1) & 1)))
                    + (size_t)(j * 32 + w) * 1024 + lane * 16;
          asm volatile("global_store_dwordx4 %0, %1, off sc1" :: "v"(dst), "v"(qv) : "memory");
        } else if (wave == 5 || wave == 6) {
          // h_seq[:, t+1, w*32..+32) for n-tile j (2 waves x 16B/lane)
          const int idx = (wave - 5) * 64 + lane;
          const int b2 = j * 16 + (idx >> 3), sg = idx & 7;
          float* hd = out_hseq + ((size_t)b2 * 2048 + (size_t)(t + 1)) * 1024 + w * 32 + sg * 4;
          *(f32x4_t*)hd = *(const f32x4_t*)(hs + b2 * 36 + sg * 4);
        }
      }
    }
  }
}

// ---------------------------- launch ----------------------------

extern "C" void kernel_launch(void* const* d_in, const int* in_sizes, int n_in,
                              void* d_out, int out_size, void* d_ws, size_t ws_size,
                              hipStream_t stream) {
  const float* initial_state = (const float*)d_in[0];
  const float* rnn_input     = (const float*)d_in[1];
  const float* enc_w0        = (const float*)d_in[2];
  const float* enc_b0        = (const float*)d_in[3];
  const float* enc_w1        = (const float*)d_in[4];
  const float* enc_b1        = (const float*)d_in[5];
  const float* enc_w2        = (const float*)d_in[6];
  const float* enc_b2        = (const float*)d_in[7];
  const float* w_ih          = (const float*)d_in[8];
  const float* w_hh          = (const float*)d_in[9];
  const float* bias          = (const float*)d_in[10];

  char* ws = (char*)d_ws;
  unsigned short* hbuf  = (unsigned short*)(ws + WS_HBUF);
  unsigned short* Wshuf = (unsigned short*)(ws + WS_WSHUF);
  unsigned short* WaugI = (unsigned short*)(ws + WS_WAUG);
  unsigned short* Xhat  = (unsigned short*)(ws + WS_XHAT);
  float*          h1    = (float*)(ws + WS_H1);
  float*          h2    = (float*)(ws + WS_H2);
  float*          out   = (float*)d_out;

  flumen_scrub<<<32, 512, 0, stream>>>((unsigned int*)hbuf);
  flumen_enc1<<<64, 512, 0, stream>>>(initial_state, enc_w0, enc_b0, h1);
  flumen_enc2<<<8, 512, 0, stream>>>(h1, enc_w1, enc_b1, h2);
  flumen_enc3<<<16, 512, 0, stream>>>(h2, enc_w2, enc_b2, out, hbuf);
  flumen_wshuf<<<1024, 512, 0, stream>>>(w_hh, Wshuf);
  flumen_waugi<<<32, 512, 0, stream>>>(w_ih, bias, WaugI);
  flumen_convx<<<2048, 512, 0, stream>>>(rnn_input, Xhat);
  flumen_lstm<<<32, 512, 0, stream>>>(Wshuf, WaugI, Xhat, hbuf, out);
}